// Round 19
// baseline (232.953 us; speedup 1.0000x reference)
//
#include <hip/hip_runtime.h>
#include <cstdint>

typedef unsigned int u32;
typedef unsigned long long u64;

#define BATCH 8
#define H 1024
#define W 1024
#define HW (H*W)
#define NPIX (BATCH*HW)
#define KTOP 2048
#define NBIN 8192
#define KEYCAP 8192
#define CAPP 131072
#define CAPC 65536
#define TARGET 2080

#define D9 1e-3f
#define DV 1e-4f

// fused tile geometry
#define TOX 64
#define TOY 32
#define CCX 72
#define CCY 36
#define SCSTR 76
#define SIROWS 68
#define SICOLS 104
#define SISTR 104
#define NJT 3
#define CAPB 768

// padded misc counters (64B apart)
#define MP(b) ((b)*16)
#define MC(b) (128 + (b)*16)
#define MK(b) (256 + (b)*16)
#define MT(b) (384 + (b)*16)

// ws layout (bytes); [0, OFF_PASS) memset to 0 each launch (4 KB)
#define OFF_MISC 0
#define OFF_PASS 4096
#define OFF_CHK  (OFF_PASS + (size_t)BATCH*CAPP*8)
#define OFF_KEY  (OFF_CHK  + (size_t)BATCH*CAPC*8)

#define LD4(p) (*reinterpret_cast<const float4*>(p))
#define ST4(p,v) (*reinterpret_cast<float4*>(p) = (v))

// ---------------- f64 dilated conv + relu (IDENTICAL to green rounds 3-18) ----------------
__device__ __forceinline__ double conv_resp_f64(
    const float* __restrict__ in, const float* __restrict__ wc,
    const float* __restrict__ wsw, int b, int y, int x)
{
  const float* base = in + (size_t)b * 3 * HW;
  const float* Sp = base;
  const float* Cp = base + HW;
  double resp = 0.0;
  const int dil[3] = {1, 4, 16};
  #pragma unroll
  for (int di = 0; di < 3; ++di) {
    int d = dil[di];
    double ac = 0.0, as = 0.0;
    #pragma unroll
    for (int ky = 0; ky < 3; ++ky) {
      int yy = y + (ky - 1) * d;
      bool yok = ((unsigned)yy < (unsigned)H);
      #pragma unroll
      for (int kx = 0; kx < 3; ++kx) {
        int xx = x + (kx - 1) * d;
        bool ok = yok && ((unsigned)xx < (unsigned)W);
        double a  = ok ? (double)Cp[yy * W + xx] : 0.0;
        double s2 = ok ? (double)Sp[yy * W + xx] : 0.0;
        ac = fma(a,  (double)wc[di * 9 + ky * 3 + kx], ac);
        as = fma(s2, (double)wsw[di * 9 + ky * 3 + kx], as);
      }
    }
    resp += ac;
    resp += as;
  }
  return resp > 0.0 ? resp : 0.0;
}

__device__ __forceinline__ u64 make_key(double val, int p) {
  u64 dbits = __double_as_longlong(val);
  return (dbits & ~0xFFFFFull) | (u64)((~(u32)p) & 0xFFFFFu);
}

// ---------------- stage one channel into LDS with zero-filled halo ----------------
__device__ __forceinline__ void stage_ch(
    float* sIn, const float* __restrict__ src, int tx0, int ty0, int tid)
{
  const int NG = (SIROWS * SICOLS) / 4;
  for (int g = tid; g < NG; g += 256) {
    int r = g / (SICOLS / 4);
    int c4 = (g - r * (SICOLS / 4)) * 4;
    int gy = ty0 - 18 + r;
    int gx0 = tx0 - 20 + c4;
    float4 v = make_float4(0.f, 0.f, 0.f, 0.f);
    if ((unsigned)gy < (unsigned)H) {
      if (gx0 >= 0 && gx0 + 3 < W) {
        v = LD4(src + gy * W + gx0);
      } else {
        float t[4];
        #pragma unroll
        for (int i = 0; i < 4; ++i) {
          int gx = gx0 + i;
          t[i] = ((unsigned)gx < (unsigned)W) ? src[gy * W + gx] : 0.f;
        }
        v = make_float4(t[0], t[1], t[2], t[3]);
      }
    }
    *reinterpret_cast<float4*>(&sIn[r * SISTR + c4]) = v;
  }
}

// ------- accumulate 27 taps (one channel), 4 outputs/thread via b128 LDS reads -------
__device__ __forceinline__ void accum_taps4(
    const float* sIn, const float* __restrict__ wp, float part[NJT][4], int tid)
{
  #pragma unroll
  for (int k = 0; k < NJT; ++k) {
    int j = k * 256 + tid;
    if (j < (CCX / 4) * CCY) {
      int cr = j / (CCX / 4);
      int cc0 = (j - cr * (CCX / 4)) * 4;
      const float* base = sIn + (cr + 16) * SISTR + cc0 + 16;

      float4 a1L = LD4(base - SISTR - 4),      a1M = LD4(base - SISTR),      a1R = LD4(base - SISTR + 4);
      float4 b1L = LD4(base + SISTR - 4),      b1M = LD4(base + SISTR),      b1R = LD4(base + SISTR + 4);
      float4 a4L = LD4(base - 4 * SISTR - 4),  a4M = LD4(base - 4 * SISTR),  a4R = LD4(base - 4 * SISTR + 4);
      float4 b4L = LD4(base + 4 * SISTR - 4),  b4M = LD4(base + 4 * SISTR),  b4R = LD4(base + 4 * SISTR + 4);
      float4 gAa = LD4(base - 16 * SISTR - 16), gAm = LD4(base - 16 * SISTR), gAb = LD4(base - 16 * SISTR + 16);
      float4 gBa = LD4(base + 16 * SISTR - 16), gBm = LD4(base + 16 * SISTR), gBb = LD4(base + 16 * SISTR + 16);
      float4 zA = LD4(base - 16), zL = LD4(base - 4), zM = LD4(base), zR = LD4(base + 4), zB = LD4(base + 16);

      float wm1[12] = {a1L.x,a1L.y,a1L.z,a1L.w, a1M.x,a1M.y,a1M.z,a1M.w, a1R.x,a1R.y,a1R.z,a1R.w};
      float wp1[12] = {b1L.x,b1L.y,b1L.z,b1L.w, b1M.x,b1M.y,b1M.z,b1M.w, b1R.x,b1R.y,b1R.z,b1R.w};
      float wm4[12] = {a4L.x,a4L.y,a4L.z,a4L.w, a4M.x,a4M.y,a4M.z,a4M.w, a4R.x,a4R.y,a4R.z,a4R.w};
      float wp4[12] = {b4L.x,b4L.y,b4L.z,b4L.w, b4M.x,b4M.y,b4M.z,b4M.w, b4R.x,b4R.y,b4R.z,b4R.w};
      float wz [12] = {zL.x,zL.y,zL.z,zL.w, zM.x,zM.y,zM.z,zM.w, zR.x,zR.y,zR.z,zR.w};
      float vAa[4] = {gAa.x,gAa.y,gAa.z,gAa.w};
      float vAm[4] = {gAm.x,gAm.y,gAm.z,gAm.w};
      float vAb[4] = {gAb.x,gAb.y,gAb.z,gAb.w};
      float vBa[4] = {gBa.x,gBa.y,gBa.z,gBa.w};
      float vBm[4] = {gBm.x,gBm.y,gBm.z,gBm.w};
      float vBb[4] = {gBb.x,gBb.y,gBb.z,gBb.w};
      float vzA[4] = {zA.x,zA.y,zA.z,zA.w};
      float vzB[4] = {zB.x,zB.y,zB.z,zB.w};

      #pragma unroll
      for (int i = 0; i < 4; ++i) {
        float ac = 0.f;
        ac = fmaf(wm1[i + 3], wp[0], ac);
        ac = fmaf(wm1[i + 4], wp[1], ac);
        ac = fmaf(wm1[i + 5], wp[2], ac);
        ac = fmaf(wz [i + 3], wp[3], ac);
        ac = fmaf(wz [i + 4], wp[4], ac);
        ac = fmaf(wz [i + 5], wp[5], ac);
        ac = fmaf(wp1[i + 3], wp[6], ac);
        ac = fmaf(wp1[i + 4], wp[7], ac);
        ac = fmaf(wp1[i + 5], wp[8], ac);
        float a = ac;
        ac = 0.f;
        ac = fmaf(wm4[i + 0], wp[9],  ac);
        ac = fmaf(wm4[i + 4], wp[10], ac);
        ac = fmaf(wm4[i + 8], wp[11], ac);
        ac = fmaf(wz [i + 0], wp[12], ac);
        ac = fmaf(wz [i + 4], wp[13], ac);
        ac = fmaf(wz [i + 8], wp[14], ac);
        ac = fmaf(wp4[i + 0], wp[15], ac);
        ac = fmaf(wp4[i + 4], wp[16], ac);
        ac = fmaf(wp4[i + 8], wp[17], ac);
        a += ac;
        ac = 0.f;
        ac = fmaf(vAa[i], wp[18], ac);
        ac = fmaf(vAm[i], wp[19], ac);
        ac = fmaf(vAb[i], wp[20], ac);
        ac = fmaf(vzA[i], wp[21], ac);
        ac = fmaf(wz[i + 4], wp[22], ac);
        ac = fmaf(vzB[i], wp[23], ac);
        ac = fmaf(vBa[i], wp[24], ac);
        ac = fmaf(vBm[i], wp[25], ac);
        ac = fmaf(vBb[i], wp[26], ac);
        a += ac;
        part[k][i] += a;
      }
    }
  }
}

// ---------------- fused kernel: staged conv + outputs + vectorized screen ----------------
__global__ __launch_bounds__(256, 4) void conv_screen_kernel(
    const float* __restrict__ in, const float* __restrict__ wc,
    const float* __restrict__ wsw, float* __restrict__ out0,
    float* __restrict__ convr, u64* __restrict__ passlist,
    u64* __restrict__ checklist, u32* __restrict__ misc)
{
  __shared__ __align__(16) float uni[SIROWS * SISTR];

  float* sIn = uni;
  float (*sconv)[SCSTR] = (float (*)[SCSTR])uni;
  u64* pbuf = (u64*)(uni + 2752);
  u64* cbuf = (u64*)(uni + 2752 + 2 * CAPB);
  u32* lcnt = (u32*)(uni + 2752 + 4 * CAPB);

  int b = blockIdx.z;
  int tx0 = blockIdx.x * TOX;
  int ty0 = blockIdx.y * TOY;
  int tid = threadIdx.x;
  const float* Sp = in + (size_t)b * 3 * HW;
  const float* Cp = Sp + HW;
  const float* Rp = Sp + 2 * HW;
  float* ob = out0 + (size_t)b * 3 * HW;
  float* cb = convr + (size_t)b * HW;

  #pragma unroll
  for (int r = 0; r < (TOX * TOY) / 4 / 256; ++r) {
    int idx = r * 256 + tid;
    int ly = idx / (TOX / 4);
    int lx4 = (idx - ly * (TOX / 4)) * 4;
    int p0 = (ty0 + ly) * W + tx0 + lx4;
    float4 S4 = LD4(Sp + p0);
    float4 C4 = LD4(Cp + p0);
    float4 R4 = LD4(Rp + p0);
    ST4(ob + p0, S4);
    ST4(ob + HW + p0, C4);
    float4 E4 = make_float4(expf(R4.x) - 1.f, expf(R4.y) - 1.f,
                            expf(R4.z) - 1.f, expf(R4.w) - 1.f);
    ST4(ob + 2 * HW + p0, E4);
  }

  float part[NJT][4];
  #pragma unroll
  for (int k = 0; k < NJT; ++k)
    #pragma unroll
    for (int i = 0; i < 4; ++i) part[k][i] = 0.f;

  stage_ch(sIn, Cp, tx0, ty0, tid);
  __syncthreads();
  accum_taps4(sIn, wc, part, tid);
  __syncthreads();
  stage_ch(sIn, Sp, tx0, ty0, tid);
  __syncthreads();
  accum_taps4(sIn, wsw, part, tid);
  __syncthreads();

  if (tid < 4) lcnt[tid] = 0;
  #pragma unroll
  for (int k = 0; k < NJT; ++k) {
    int j = k * 256 + tid;
    if (j < (CCX / 4) * CCY) {
      int cr = j / (CCX / 4);
      int cc0 = (j - cr * (CCX / 4)) * 4;
      float4 rv = make_float4(fmaxf(part[k][0], 0.f), fmaxf(part[k][1], 0.f),
                              fmaxf(part[k][2], 0.f), fmaxf(part[k][3], 0.f));
      *reinterpret_cast<float4*>(&sconv[cr][cc0]) = rv;
      if (cr >= 2 && cr <= CCY - 3 && cc0 >= 4 && cc0 <= 64) {
        int gy = ty0 - 2 + cr, gx0 = tx0 - 4 + cc0;
        ST4(cb + gy * W + gx0, rv);
      }
    }
  }
  __syncthreads();

  // ---- vectorized in-LDS screen: 4 px/thread, 15 aligned f4 window loads ----
  #pragma unroll
  for (int r = 0; r < (TOX * TOY) / 4 / 256; ++r) {
    int j4 = r * 256 + tid;             // 0..511
    int ly = j4 >> 4;                   // 0..31
    int lx4 = (j4 & 15) * 4;            // 0,4,...,60
    int ybase = ty0 + ly;

    float rw[5][12];
    #pragma unroll
    for (int rr = 0; rr < 5; ++rr) {
      float4 A  = LD4(&sconv[ly + rr][lx4]);
      float4 Bq = LD4(&sconv[ly + rr][lx4 + 4]);
      float4 Cq = LD4(&sconv[ly + rr][lx4 + 8]);
      rw[rr][0]=A.x;  rw[rr][1]=A.y;  rw[rr][2]=A.z;  rw[rr][3]=A.w;
      rw[rr][4]=Bq.x; rw[rr][5]=Bq.y; rw[rr][6]=Bq.z; rw[rr][7]=Bq.w;
      rw[rr][8]=Cq.x; rw[rr][9]=Cq.y; rw[rr][10]=Cq.z; rw[rr][11]=Cq.w;
    }

    float vs0[8], vs1[8], vs2[8];
    #pragma unroll
    for (int c = 0; c < 8; ++c) {
      vs0[c] = rw[0][c + 2] + rw[1][c + 2] + rw[2][c + 2];
      vs1[c] = rw[1][c + 2] + rw[2][c + 2] + rw[3][c + 2];
      vs2[c] = rw[2][c + 2] + rw[3][c + 2] + rw[4][c + 2];
    }
    float hs0[6], hs1[6], hs2[6];
    #pragma unroll
    for (int c = 0; c < 6; ++c) {
      hs0[c] = vs0[c] + vs0[c + 1] + vs0[c + 2];
      hs1[c] = vs1[c] + vs1[c + 1] + vs1[c + 2];
      hs2[c] = vs2[c] + vs2[c + 1] + vs2[c + 2];
    }

    #pragma unroll
    for (int i = 0; i < 4; ++i) {
      int x = tx0 + lx4 + i;
      int y = ybase;
      bool act = (y >= 5 && y <= H - 6 && x >= 5 && x <= W - 6);
      bool cand = false, pass = false;
      float val = 0.f;
      if (act) {
        float sc9 = hs1[i + 1];
        val = rw[2][i + 4];
        float m9 = fmaxf(fmaxf(fmaxf(hs0[i], hs0[i + 1]), fmaxf(hs0[i + 2], hs1[i])),
                         fmaxf(fmaxf(hs1[i + 2], hs2[i]), fmaxf(hs2[i + 1], hs2[i + 2])));
        cand = !((sc9 < 0.9f - D9) || (sc9 < m9 - D9) || (val < 0.1f - DV));
        pass = cand && (sc9 > 0.9f + D9) && (sc9 >= m9 + D9) && (val > 0.1f + DV);
      }

      u64 entry = ((u64)__float_as_uint(val) << 32) | (u32)(y * W + x);
      if (pass) {
        u32 pos = atomicAdd(&lcnt[0], 1u);
        if (pos < CAPB) pbuf[pos] = entry;
        else {
          u32 g = atomicAdd(&misc[MP(b)], 1u);
          if (g < CAPP) passlist[(size_t)b * CAPP + g] = entry;
        }
      } else if (cand) {
        u32 pos = atomicAdd(&lcnt[1], 1u);
        if (pos < CAPB) cbuf[pos] = entry;
        else {
          u32 g = atomicAdd(&misc[MC(b)], 1u);
          if (g < CAPC) checklist[(size_t)b * CAPC + g] = entry;
        }
      }
    }
  }
  __syncthreads();

  u32 np = min(lcnt[0], (u32)CAPB);
  u32 nc = min(lcnt[1], (u32)CAPB);
  if (tid == 0) lcnt[2] = np ? atomicAdd(&misc[MP(b)], np) : 0u;
  if (tid == 1) lcnt[3] = nc ? atomicAdd(&misc[MC(b)], nc) : 0u;
  __syncthreads();
  u32 pbase = lcnt[2], cbase = lcnt[3];

  for (u32 i = tid; i < np; i += 256) {
    u32 g = pbase + i;
    if (g < CAPP) passlist[(size_t)b * CAPP + g] = pbuf[i];
  }
  for (u32 i = tid; i < nc; i += 256) {
    u32 g = cbase + i;
    if (g < CAPC) checklist[(size_t)b * CAPC + g] = cbuf[i];
  }
}

// ------- cutscan: LDS hist from passlist valbits -> suffix scan -> cut ----------
__global__ __launch_bounds__(1024) void cutscan_kernel(
    const u64* __restrict__ passlist, u32* __restrict__ misc)
{
  __shared__ u32 sfx[NBIN + NBIN / 32];
  #define SX(i) sfx[(i) + ((i) >> 5)]
  int b = blockIdx.x;
  int tid = threadIdx.x;

  #pragma unroll
  for (int k = 0; k < 8; ++k) SX(tid * 8 + k) = 0u;
  __syncthreads();

  int np = (int)min(misc[MP(b)], (u32)CAPP);
  const u64* L = passlist + (size_t)b * CAPP;
  for (int i = tid; i < np; i += 1024) {
    u32 vb = (u32)(L[i] >> 32);
    u32 bin = vb >> 19;
    atomicAdd(&sfx[bin + (bin >> 5)], 1u);
  }
  __syncthreads();

  for (int off = 1; off < NBIN; off <<= 1) {
    u32 t[8];
    #pragma unroll
    for (int k = 0; k < 8; ++k) {
      int i = tid * 8 + k;
      t[k] = (i + off < NBIN) ? SX(i + off) : 0u;
    }
    __syncthreads();
    #pragma unroll
    for (int k = 0; k < 8; ++k) SX(tid * 8 + k) += t[k];
    __syncthreads();
  }

  if (SX(0) < TARGET) return;

  #pragma unroll
  for (int k = 0; k < 8; ++k) {
    int i = tid * 8 + k;
    u32 s = SX(i);
    u32 nxt = (i + 1 < NBIN) ? SX(i + 1) : 0u;
    if (s >= TARGET && nxt < TARGET) {
      u32 cutbin = (i > 0) ? (u32)(i - 1) : 0u;
      misc[MT(b)] = cutbin << 19;
    }
  }
  #undef SX
}

// ------- exact: keygen (pass-peaks) + recheck (uncertain) in one dispatch ----------
__global__ __launch_bounds__(1024) void exact_kernel(
    const float* __restrict__ in, const float* __restrict__ wc,
    const float* __restrict__ wsw, const u64* __restrict__ passlist,
    const u64* __restrict__ checklist, u32* __restrict__ misc,
    u64* __restrict__ keybuf)
{
  int b = blockIdx.y;
  int sub = blockIdx.x;            // 0..15
  int tid = threadIdx.x;
  u32 cutb = misc[MT(b)];
  int lane = tid & 63;

  int np = (int)min(misc[MP(b)], (u32)CAPP);
  for (int i = sub * 1024 + tid; i < np; i += 16 * 1024) {
    u64 e = passlist[(size_t)b * CAPP + i];
    bool keep = ((u32)(e >> 32)) >= cutb;
    u64 k64 = 0;
    if (keep) {
      int p = (int)(e & 0xFFFFFu);
      k64 = make_key(conv_resp_f64(in, wc, wsw, b, p >> 10, p & (W - 1)), p);
    }
    u64 km = __ballot(keep);
    if (keep) {
      int leader = __ffsll((unsigned long long)km) - 1;
      u32 base = 0;
      if (lane == leader) base = atomicAdd(&misc[MK(b)], (u32)__popcll(km));
      base = __shfl(base, leader);
      u32 rk = (u32)__popcll(km & ((1ull << lane) - 1ull));
      if (base + rk < KEYCAP) keybuf[(size_t)b * KEYCAP + base + rk] = k64;
    }
  }

  int nc = (int)min(misc[MC(b)], (u32)CAPC);
  int wid = sub * 16 + (tid >> 6);
  for (int i = wid; i < nc; i += 256) {
    u64 e = checklist[(size_t)b * CAPC + i];
    if (((u32)(e >> 32)) < cutb) continue;
    int p = (int)(e & 0xFFFFFu);
    int y = p >> 10, x = p & (W - 1);

    double v = 0.0;
    if (lane < 25)
      v = conv_resp_f64(in, wc, wsw, b, y + lane / 5 - 2, x + lane % 5 - 2);

    double c[25];
    #pragma unroll
    for (int k = 0; k < 25; ++k) c[k] = __shfl(v, k);

    double cs0[5], cs1[5], cs2[5];
    #pragma unroll
    for (int j = 0; j < 5; ++j) {
      cs0[j] = c[0 + j] + c[5 + j] + c[10 + j];
      cs1[j] = c[5 + j] + c[10 + j] + c[15 + j];
      cs2[j] = c[10 + j] + c[15 + j] + c[20 + j];
    }
    double val = c[12];

    double sc = (cs1[1] + cs1[2] + cs1[3]) * (1.0 / 9.0);
    if (!(sc > 0.1)) continue;
    bool pk = true;
    #pragma unroll
    for (int j = 0; j < 3; ++j) {
      pk = pk && (sc >= (cs0[j] + cs0[j + 1] + cs0[j + 2]) * (1.0 / 9.0));
      pk = pk && (sc >= (cs2[j] + cs2[j + 1] + cs2[j + 2]) * (1.0 / 9.0));
    }
    pk = pk && (sc >= (cs1[0] + cs1[1] + cs1[2]) * (1.0 / 9.0));
    pk = pk && (sc >= (cs1[2] + cs1[3] + cs1[4]) * (1.0 / 9.0));
    if (!pk) continue;
    if (!(val > 0.1)) continue;

    if (lane == 0) {
      u32 pos = atomicAdd(&misc[MK(b)], 1u);
      if (pos < KEYCAP) keybuf[(size_t)b * KEYCAP + pos] = make_key(val, p);
    }
  }
}

// ------- chunk_sort: per-1024-chunk bitonic sort desc (64 blocks) ----------
__global__ __launch_bounds__(1024) void chunk_sort_kernel(
    u64* __restrict__ keybuf, const u32* __restrict__ misc)
{
  __shared__ u64 ck[1024];
  int b = blockIdx.y;
  int c = blockIdx.x;
  int tid = threadIdx.x;
  int M = (int)min(misc[MK(b)], (u32)KEYCAP);
  u64* base = keybuf + (size_t)b * KEYCAP;
  int gi = c * 1024 + tid;
  ck[tid] = (gi < M) ? base[gi] : 0ULL;
  __syncthreads();

  for (int k = 2; k <= 1024; k <<= 1) {
    for (int j = k >> 1; j > 0; j >>= 1) {
      int l = tid ^ j;
      if (l > tid) {
        u64 a = ck[tid], bb = ck[l];
        bool up = ((tid & k) == 0);
        bool sw = up ? (a < bb) : (a > bb);   // descending overall
        if (sw) { ck[tid] = bb; ck[l] = a; }
      }
      __syncthreads();
    }
  }
  base[gi] = ck[tid];
}

// ------- merge_rank: exact global rank via binary searches -> emit center_pred -------
__global__ __launch_bounds__(1024) void merge_rank_kernel(
    const u64* __restrict__ keybuf, const u32* __restrict__ misc,
    const float* __restrict__ convr, float* __restrict__ center)
{
  __shared__ u64 sk[KEYCAP];
  int b = blockIdx.x;
  int tid = threadIdx.x;
  const u64* kb = keybuf + (size_t)b * KEYCAP;
  for (int i = tid; i < KEYCAP; i += 1024) sk[i] = kb[i];

  float* cb = center + (size_t)b * KTOP * 5;
  for (int i = tid; i < KTOP * 5; i += 1024) cb[i] = 0.f;
  __syncthreads();

  #pragma unroll
  for (int e = 0; e < KEYCAP / 1024; ++e) {
    int i = e * 1024 + tid;
    u64 k = sk[i];
    if (k == 0ULL) continue;
    int myc = i >> 10;
    int rank = i & 1023;
    #pragma unroll
    for (int c = 0; c < 8; ++c) {
      if (c == myc) continue;
      const u64* arr = &sk[c << 10];
      int lo = 0, hi = 1024;
      while (lo < hi) {
        int mid = (lo + hi) >> 1;
        if (arr[mid] > k) lo = mid + 1; else hi = mid;
      }
      rank += lo;
    }
    if (rank < KTOP) {
      u32 p = (~(u32)k) & 0xFFFFFu;
      float v = convr[(size_t)b * HW + p];
      float* o = cb + (size_t)rank * 5;
      o[0] = 1.0f;
      o[1] = (float)(p & (W - 1));
      o[2] = (float)(p >> 10);
      o[3] = v;
      o[4] = v;
    }
  }
}

extern "C" void kernel_launch(void* const* d_in, const int* in_sizes, int n_in,
                              void* d_out, int out_size, void* d_ws, size_t ws_size,
                              hipStream_t stream) {
  const float* in  = (const float*)d_in[0];
  const float* wc  = (const float*)d_in[1];
  const float* wsw = (const float*)d_in[2];

  float* out0   = (float*)d_out;                     // (8,3,1024,1024)
  float* center = out0 + (size_t)BATCH * 3 * HW;     // (8,2048,5)
  float* convr  = center + (size_t)BATCH * KTOP * 5; // (8,1,1024,1024)

  char* w = (char*)d_ws;
  u32* misc      = (u32*)(w + OFF_MISC);
  u64* passlist  = (u64*)(w + OFF_PASS);
  u64* checklist = (u64*)(w + OFF_CHK);
  u64* keybuf    = (u64*)(w + OFF_KEY);

  hipMemsetAsync(w, 0, OFF_PASS, stream);  // misc only (4 KB)

  conv_screen_kernel<<<dim3(W / TOX, H / TOY, BATCH), 256, 0, stream>>>(
      in, wc, wsw, out0, convr, passlist, checklist, misc);
  cutscan_kernel<<<BATCH, 1024, 0, stream>>>(passlist, misc);
  exact_kernel<<<dim3(16, BATCH), 1024, 0, stream>>>(
      in, wc, wsw, passlist, checklist, misc, keybuf);
  chunk_sort_kernel<<<dim3(KEYCAP / 1024, BATCH), 1024, 0, stream>>>(keybuf, misc);
  merge_rank_kernel<<<BATCH, 1024, 0, stream>>>(keybuf, misc, convr, center);
}

// Round 20
// 225.802 us; speedup vs baseline: 1.0317x; 1.0317x over previous
//
#include <hip/hip_runtime.h>
#include <cstdint>

typedef unsigned int u32;
typedef unsigned long long u64;

#define BATCH 8
#define H 1024
#define W 1024
#define HW (H*W)
#define NPIX (BATCH*HW)
#define KTOP 2048
#define NBIN 8192
#define KEYCAP 8192
#define CAPP 131072
#define CAPC 65536
#define TARGET 2080

#define D9 1e-3f
#define DV 1e-4f

// fused tile geometry
#define TOX 64
#define TOY 32
#define CCX 72
#define CCY 36
#define SCSTR 76
#define SIROWS 68
#define SICOLS 104
#define SISTR 104
#define NJT 3
#define CAPB 768

// padded misc counters (64B apart)
#define MP(b) ((b)*16)
#define MC(b) (128 + (b)*16)
#define MK(b) (256 + (b)*16)
#define MT(b) (384 + (b)*16)

// ws layout (bytes); [0, OFF_PASS) memset to 0 each launch (4 KB)
#define OFF_MISC 0
#define OFF_PASS 4096
#define OFF_CHK  (OFF_PASS + (size_t)BATCH*CAPP*8)
#define OFF_KEY  (OFF_CHK  + (size_t)BATCH*CAPC*8)

#define LD4(p) (*reinterpret_cast<const float4*>(p))
#define ST4(p,v) (*reinterpret_cast<float4*>(p) = (v))

// ---------------- f64 dilated conv + relu (IDENTICAL to green rounds 3-19) ----------------
__device__ __forceinline__ double conv_resp_f64(
    const float* __restrict__ in, const float* __restrict__ wc,
    const float* __restrict__ wsw, int b, int y, int x)
{
  const float* base = in + (size_t)b * 3 * HW;
  const float* Sp = base;
  const float* Cp = base + HW;
  double resp = 0.0;
  const int dil[3] = {1, 4, 16};
  #pragma unroll
  for (int di = 0; di < 3; ++di) {
    int d = dil[di];
    double ac = 0.0, as = 0.0;
    #pragma unroll
    for (int ky = 0; ky < 3; ++ky) {
      int yy = y + (ky - 1) * d;
      bool yok = ((unsigned)yy < (unsigned)H);
      #pragma unroll
      for (int kx = 0; kx < 3; ++kx) {
        int xx = x + (kx - 1) * d;
        bool ok = yok && ((unsigned)xx < (unsigned)W);
        double a  = ok ? (double)Cp[yy * W + xx] : 0.0;
        double s2 = ok ? (double)Sp[yy * W + xx] : 0.0;
        ac = fma(a,  (double)wc[di * 9 + ky * 3 + kx], ac);
        as = fma(s2, (double)wsw[di * 9 + ky * 3 + kx], as);
      }
    }
    resp += ac;
    resp += as;
  }
  return resp > 0.0 ? resp : 0.0;
}

__device__ __forceinline__ u64 make_key(double val, int p) {
  u64 dbits = __double_as_longlong(val);
  return (dbits & ~0xFFFFFull) | (u64)((~(u32)p) & 0xFFFFFu);
}

// ---------------- stage one channel into LDS with zero-filled halo ----------------
__device__ __forceinline__ void stage_ch(
    float* sIn, const float* __restrict__ src, int tx0, int ty0, int tid)
{
  const int NG = (SIROWS * SICOLS) / 4;
  for (int g = tid; g < NG; g += 256) {
    int r = g / (SICOLS / 4);
    int c4 = (g - r * (SICOLS / 4)) * 4;
    int gy = ty0 - 18 + r;
    int gx0 = tx0 - 20 + c4;
    float4 v = make_float4(0.f, 0.f, 0.f, 0.f);
    if ((unsigned)gy < (unsigned)H) {
      if (gx0 >= 0 && gx0 + 3 < W) {
        v = LD4(src + gy * W + gx0);
      } else {
        float t[4];
        #pragma unroll
        for (int i = 0; i < 4; ++i) {
          int gx = gx0 + i;
          t[i] = ((unsigned)gx < (unsigned)W) ? src[gy * W + gx] : 0.f;
        }
        v = make_float4(t[0], t[1], t[2], t[3]);
      }
    }
    *reinterpret_cast<float4*>(&sIn[r * SISTR + c4]) = v;
  }
}

// ------- accumulate 27 taps (one channel), 4 outputs/thread via b128 LDS reads -------
__device__ __forceinline__ void accum_taps4(
    const float* sIn, const float* __restrict__ wp, float part[NJT][4], int tid)
{
  #pragma unroll
  for (int k = 0; k < NJT; ++k) {
    int j = k * 256 + tid;
    if (j < (CCX / 4) * CCY) {
      int cr = j / (CCX / 4);
      int cc0 = (j - cr * (CCX / 4)) * 4;
      const float* base = sIn + (cr + 16) * SISTR + cc0 + 16;

      float4 a1L = LD4(base - SISTR - 4),      a1M = LD4(base - SISTR),      a1R = LD4(base - SISTR + 4);
      float4 b1L = LD4(base + SISTR - 4),      b1M = LD4(base + SISTR),      b1R = LD4(base + SISTR + 4);
      float4 a4L = LD4(base - 4 * SISTR - 4),  a4M = LD4(base - 4 * SISTR),  a4R = LD4(base - 4 * SISTR + 4);
      float4 b4L = LD4(base + 4 * SISTR - 4),  b4M = LD4(base + 4 * SISTR),  b4R = LD4(base + 4 * SISTR + 4);
      float4 gAa = LD4(base - 16 * SISTR - 16), gAm = LD4(base - 16 * SISTR), gAb = LD4(base - 16 * SISTR + 16);
      float4 gBa = LD4(base + 16 * SISTR - 16), gBm = LD4(base + 16 * SISTR), gBb = LD4(base + 16 * SISTR + 16);
      float4 zA = LD4(base - 16), zL = LD4(base - 4), zM = LD4(base), zR = LD4(base + 4), zB = LD4(base + 16);

      float wm1[12] = {a1L.x,a1L.y,a1L.z,a1L.w, a1M.x,a1M.y,a1M.z,a1M.w, a1R.x,a1R.y,a1R.z,a1R.w};
      float wp1[12] = {b1L.x,b1L.y,b1L.z,b1L.w, b1M.x,b1M.y,b1M.z,b1M.w, b1R.x,b1R.y,b1R.z,b1R.w};
      float wm4[12] = {a4L.x,a4L.y,a4L.z,a4L.w, a4M.x,a4M.y,a4M.z,a4M.w, a4R.x,a4R.y,a4R.z,a4R.w};
      float wp4[12] = {b4L.x,b4L.y,b4L.z,b4L.w, b4M.x,b4M.y,b4M.z,b4M.w, b4R.x,b4R.y,b4R.z,b4R.w};
      float wz [12] = {zL.x,zL.y,zL.z,zL.w, zM.x,zM.y,zM.z,zM.w, zR.x,zR.y,zR.z,zR.w};
      float vAa[4] = {gAa.x,gAa.y,gAa.z,gAa.w};
      float vAm[4] = {gAm.x,gAm.y,gAm.z,gAm.w};
      float vAb[4] = {gAb.x,gAb.y,gAb.z,gAb.w};
      float vBa[4] = {gBa.x,gBa.y,gBa.z,gBa.w};
      float vBm[4] = {gBm.x,gBm.y,gBm.z,gBm.w};
      float vBb[4] = {gBb.x,gBb.y,gBb.z,gBb.w};
      float vzA[4] = {zA.x,zA.y,zA.z,zA.w};
      float vzB[4] = {zB.x,zB.y,zB.z,zB.w};

      #pragma unroll
      for (int i = 0; i < 4; ++i) {
        float ac = 0.f;
        ac = fmaf(wm1[i + 3], wp[0], ac);
        ac = fmaf(wm1[i + 4], wp[1], ac);
        ac = fmaf(wm1[i + 5], wp[2], ac);
        ac = fmaf(wz [i + 3], wp[3], ac);
        ac = fmaf(wz [i + 4], wp[4], ac);
        ac = fmaf(wz [i + 5], wp[5], ac);
        ac = fmaf(wp1[i + 3], wp[6], ac);
        ac = fmaf(wp1[i + 4], wp[7], ac);
        ac = fmaf(wp1[i + 5], wp[8], ac);
        float a = ac;
        ac = 0.f;
        ac = fmaf(wm4[i + 0], wp[9],  ac);
        ac = fmaf(wm4[i + 4], wp[10], ac);
        ac = fmaf(wm4[i + 8], wp[11], ac);
        ac = fmaf(wz [i + 0], wp[12], ac);
        ac = fmaf(wz [i + 4], wp[13], ac);
        ac = fmaf(wz [i + 8], wp[14], ac);
        ac = fmaf(wp4[i + 0], wp[15], ac);
        ac = fmaf(wp4[i + 4], wp[16], ac);
        ac = fmaf(wp4[i + 8], wp[17], ac);
        a += ac;
        ac = 0.f;
        ac = fmaf(vAa[i], wp[18], ac);
        ac = fmaf(vAm[i], wp[19], ac);
        ac = fmaf(vAb[i], wp[20], ac);
        ac = fmaf(vzA[i], wp[21], ac);
        ac = fmaf(wz[i + 4], wp[22], ac);
        ac = fmaf(vzB[i], wp[23], ac);
        ac = fmaf(vBa[i], wp[24], ac);
        ac = fmaf(vBm[i], wp[25], ac);
        ac = fmaf(vBb[i], wp[26], ac);
        a += ac;
        part[k][i] += a;
      }
    }
  }
}

// ---------------- fused kernel: staged conv + outputs + screen ----------------
__global__ __launch_bounds__(256, 5) void conv_screen_kernel(
    const float* __restrict__ in, const float* __restrict__ wc,
    const float* __restrict__ wsw, float* __restrict__ out0,
    float* __restrict__ convr, u64* __restrict__ passlist,
    u64* __restrict__ checklist, u32* __restrict__ misc)
{
  __shared__ __align__(16) float uni[SIROWS * SISTR];

  float* sIn = uni;
  float (*sconv)[SCSTR] = (float (*)[SCSTR])uni;
  u64* pbuf = (u64*)(uni + 2752);
  u64* cbuf = (u64*)(uni + 2752 + 2 * CAPB);
  u32* lcnt = (u32*)(uni + 2752 + 4 * CAPB);

  int b = blockIdx.z;
  int tx0 = blockIdx.x * TOX;
  int ty0 = blockIdx.y * TOY;
  int tid = threadIdx.x;
  const float* Sp = in + (size_t)b * 3 * HW;
  const float* Cp = Sp + HW;
  const float* Rp = Sp + 2 * HW;
  float* ob = out0 + (size_t)b * 3 * HW;
  float* cb = convr + (size_t)b * HW;

  #pragma unroll
  for (int r = 0; r < (TOX * TOY) / 4 / 256; ++r) {
    int idx = r * 256 + tid;
    int ly = idx / (TOX / 4);
    int lx4 = (idx - ly * (TOX / 4)) * 4;
    int p0 = (ty0 + ly) * W + tx0 + lx4;
    float4 S4 = LD4(Sp + p0);
    float4 C4 = LD4(Cp + p0);
    float4 R4 = LD4(Rp + p0);
    ST4(ob + p0, S4);
    ST4(ob + HW + p0, C4);
    float4 E4 = make_float4(expf(R4.x) - 1.f, expf(R4.y) - 1.f,
                            expf(R4.z) - 1.f, expf(R4.w) - 1.f);
    ST4(ob + 2 * HW + p0, E4);
  }

  float part[NJT][4];
  #pragma unroll
  for (int k = 0; k < NJT; ++k)
    #pragma unroll
    for (int i = 0; i < 4; ++i) part[k][i] = 0.f;

  stage_ch(sIn, Cp, tx0, ty0, tid);
  __syncthreads();
  accum_taps4(sIn, wc, part, tid);
  __syncthreads();
  stage_ch(sIn, Sp, tx0, ty0, tid);
  __syncthreads();
  accum_taps4(sIn, wsw, part, tid);
  __syncthreads();

  if (tid < 4) lcnt[tid] = 0;
  #pragma unroll
  for (int k = 0; k < NJT; ++k) {
    int j = k * 256 + tid;
    if (j < (CCX / 4) * CCY) {
      int cr = j / (CCX / 4);
      int cc0 = (j - cr * (CCX / 4)) * 4;
      float4 rv = make_float4(fmaxf(part[k][0], 0.f), fmaxf(part[k][1], 0.f),
                              fmaxf(part[k][2], 0.f), fmaxf(part[k][3], 0.f));
      *reinterpret_cast<float4*>(&sconv[cr][cc0]) = rv;
      if (cr >= 2 && cr <= CCY - 3 && cc0 >= 4 && cc0 <= 64) {
        int gy = ty0 - 2 + cr, gx0 = tx0 - 4 + cc0;
        ST4(cb + gy * W + gx0, rv);
      }
    }
  }
  __syncthreads();

  for (int r = 0; r < (TOX * TOY) / 256; ++r) {
    int idx = r * 256 + tid;
    int ly = idx >> 6;
    int lx = idx & 63;
    int x = tx0 + lx, y = ty0 + ly;
    bool act = (y >= 5 && y <= H - 6 && x >= 5 && x <= W - 6);

    bool cand = false, pass = false;
    float val = 0.f;
    if (act) {
      float vs0[5], vs1[5], vs2[5];
      #pragma unroll
      for (int j = 0; j < 5; ++j) {
        int c = lx + 2 + j;
        float a0 = sconv[ly + 0][c];
        float a1 = sconv[ly + 1][c];
        float a2 = sconv[ly + 2][c];
        float a3 = sconv[ly + 3][c];
        float a4 = sconv[ly + 4][c];
        vs0[j] = a0 + a1 + a2;
        vs1[j] = a1 + a2 + a3;
        vs2[j] = a2 + a3 + a4;
      }
      float hs0[3], hs1[3], hs2[3];
      #pragma unroll
      for (int j = 0; j < 3; ++j) {
        hs0[j] = vs0[j] + vs0[j + 1] + vs0[j + 2];
        hs1[j] = vs1[j] + vs1[j + 1] + vs1[j + 2];
        hs2[j] = vs2[j] + vs2[j + 1] + vs2[j + 2];
      }
      float sc9 = hs1[1];
      val = sconv[ly + 2][lx + 4];
      float m9 = fmaxf(fmaxf(fmaxf(hs0[0], hs0[1]), fmaxf(hs0[2], hs1[0])),
                       fmaxf(fmaxf(hs1[2], hs2[0]), fmaxf(hs2[1], hs2[2])));
      cand = !((sc9 < 0.9f - D9) || (sc9 < m9 - D9) || (val < 0.1f - DV));
      pass = cand && (sc9 > 0.9f + D9) && (sc9 >= m9 + D9) && (val > 0.1f + DV);
    }

    u64 entry = ((u64)__float_as_uint(val) << 32) | (u32)(y * W + x);
    if (pass) {
      u32 pos = atomicAdd(&lcnt[0], 1u);
      if (pos < CAPB) pbuf[pos] = entry;
      else {
        u32 g = atomicAdd(&misc[MP(b)], 1u);
        if (g < CAPP) passlist[(size_t)b * CAPP + g] = entry;
      }
    } else if (cand) {
      u32 pos = atomicAdd(&lcnt[1], 1u);
      if (pos < CAPB) cbuf[pos] = entry;
      else {
        u32 g = atomicAdd(&misc[MC(b)], 1u);
        if (g < CAPC) checklist[(size_t)b * CAPC + g] = entry;
      }
    }
  }
  __syncthreads();

  u32 np = min(lcnt[0], (u32)CAPB);
  u32 nc = min(lcnt[1], (u32)CAPB);
  if (tid == 0) lcnt[2] = np ? atomicAdd(&misc[MP(b)], np) : 0u;
  if (tid == 1) lcnt[3] = nc ? atomicAdd(&misc[MC(b)], nc) : 0u;
  __syncthreads();
  u32 pbase = lcnt[2], cbase = lcnt[3];

  for (u32 i = tid; i < np; i += 256) {
    u32 g = pbase + i;
    if (g < CAPP) passlist[(size_t)b * CAPP + g] = pbuf[i];
  }
  for (u32 i = tid; i < nc; i += 256) {
    u32 g = cbase + i;
    if (g < CAPC) checklist[(size_t)b * CAPC + g] = cbuf[i];
  }
}

// ------- cutscan: LDS hist from passlist valbits -> suffix scan -> cut ----------
__global__ __launch_bounds__(1024) void cutscan_kernel(
    const u64* __restrict__ passlist, u32* __restrict__ misc)
{
  __shared__ u32 sfx[NBIN + NBIN / 32];
  #define SX(i) sfx[(i) + ((i) >> 5)]
  int b = blockIdx.x;
  int tid = threadIdx.x;

  #pragma unroll
  for (int k = 0; k < 8; ++k) SX(tid * 8 + k) = 0u;
  __syncthreads();

  int np = (int)min(misc[MP(b)], (u32)CAPP);
  const u64* L = passlist + (size_t)b * CAPP;
  for (int i = tid; i < np; i += 1024) {
    u32 vb = (u32)(L[i] >> 32);
    u32 bin = vb >> 19;
    atomicAdd(&sfx[bin + (bin >> 5)], 1u);
  }
  __syncthreads();

  for (int off = 1; off < NBIN; off <<= 1) {
    u32 t[8];
    #pragma unroll
    for (int k = 0; k < 8; ++k) {
      int i = tid * 8 + k;
      t[k] = (i + off < NBIN) ? SX(i + off) : 0u;
    }
    __syncthreads();
    #pragma unroll
    for (int k = 0; k < 8; ++k) SX(tid * 8 + k) += t[k];
    __syncthreads();
  }

  if (SX(0) < TARGET) return;

  #pragma unroll
  for (int k = 0; k < 8; ++k) {
    int i = tid * 8 + k;
    u32 s = SX(i);
    u32 nxt = (i + 1 < NBIN) ? SX(i + 1) : 0u;
    if (s >= TARGET && nxt < TARGET) {
      u32 cutbin = (i > 0) ? (u32)(i - 1) : 0u;
      misc[MT(b)] = cutbin << 19;
    }
  }
  #undef SX
}

// ------- exact: keygen (pass-peaks) + recheck (uncertain) in one dispatch ----------
__global__ __launch_bounds__(1024) void exact_kernel(
    const float* __restrict__ in, const float* __restrict__ wc,
    const float* __restrict__ wsw, const u64* __restrict__ passlist,
    const u64* __restrict__ checklist, u32* __restrict__ misc,
    u64* __restrict__ keybuf)
{
  int b = blockIdx.y;
  int sub = blockIdx.x;            // 0..15
  int tid = threadIdx.x;
  u32 cutb = misc[MT(b)];
  int lane = tid & 63;

  int np = (int)min(misc[MP(b)], (u32)CAPP);
  for (int i = sub * 1024 + tid; i < np; i += 16 * 1024) {
    u64 e = passlist[(size_t)b * CAPP + i];
    bool keep = ((u32)(e >> 32)) >= cutb;
    u64 k64 = 0;
    if (keep) {
      int p = (int)(e & 0xFFFFFu);
      k64 = make_key(conv_resp_f64(in, wc, wsw, b, p >> 10, p & (W - 1)), p);
    }
    u64 km = __ballot(keep);
    if (keep) {
      int leader = __ffsll((unsigned long long)km) - 1;
      u32 base = 0;
      if (lane == leader) base = atomicAdd(&misc[MK(b)], (u32)__popcll(km));
      base = __shfl(base, leader);
      u32 rk = (u32)__popcll(km & ((1ull << lane) - 1ull));
      if (base + rk < KEYCAP) keybuf[(size_t)b * KEYCAP + base + rk] = k64;
    }
  }

  int nc = (int)min(misc[MC(b)], (u32)CAPC);
  int wid = sub * 16 + (tid >> 6);
  for (int i = wid; i < nc; i += 256) {
    u64 e = checklist[(size_t)b * CAPC + i];
    if (((u32)(e >> 32)) < cutb) continue;
    int p = (int)(e & 0xFFFFFu);
    int y = p >> 10, x = p & (W - 1);

    double v = 0.0;
    if (lane < 25)
      v = conv_resp_f64(in, wc, wsw, b, y + lane / 5 - 2, x + lane % 5 - 2);

    double c[25];
    #pragma unroll
    for (int k = 0; k < 25; ++k) c[k] = __shfl(v, k);

    double cs0[5], cs1[5], cs2[5];
    #pragma unroll
    for (int j = 0; j < 5; ++j) {
      cs0[j] = c[0 + j] + c[5 + j] + c[10 + j];
      cs1[j] = c[5 + j] + c[10 + j] + c[15 + j];
      cs2[j] = c[10 + j] + c[15 + j] + c[20 + j];
    }
    double val = c[12];

    double sc = (cs1[1] + cs1[2] + cs1[3]) * (1.0 / 9.0);
    if (!(sc > 0.1)) continue;
    bool pk = true;
    #pragma unroll
    for (int j = 0; j < 3; ++j) {
      pk = pk && (sc >= (cs0[j] + cs0[j + 1] + cs0[j + 2]) * (1.0 / 9.0));
      pk = pk && (sc >= (cs2[j] + cs2[j + 1] + cs2[j + 2]) * (1.0 / 9.0));
    }
    pk = pk && (sc >= (cs1[0] + cs1[1] + cs1[2]) * (1.0 / 9.0));
    pk = pk && (sc >= (cs1[2] + cs1[3] + cs1[4]) * (1.0 / 9.0));
    if (!pk) continue;
    if (!(val > 0.1)) continue;

    if (lane == 0) {
      u32 pos = atomicAdd(&misc[MK(b)], 1u);
      if (pos < KEYCAP) keybuf[(size_t)b * KEYCAP + pos] = make_key(val, p);
    }
  }
}

// ------- chunk_sort: per-1024-chunk bitonic sort desc (64 blocks) ----------
__global__ __launch_bounds__(1024) void chunk_sort_kernel(
    u64* __restrict__ keybuf, const u32* __restrict__ misc)
{
  __shared__ u64 ck[1024];
  int b = blockIdx.y;
  int c = blockIdx.x;
  int tid = threadIdx.x;
  int M = (int)min(misc[MK(b)], (u32)KEYCAP);
  u64* base = keybuf + (size_t)b * KEYCAP;
  int gi = c * 1024 + tid;
  ck[tid] = (gi < M) ? base[gi] : 0ULL;
  __syncthreads();

  for (int k = 2; k <= 1024; k <<= 1) {
    for (int j = k >> 1; j > 0; j >>= 1) {
      int l = tid ^ j;
      if (l > tid) {
        u64 a = ck[tid], bb = ck[l];
        bool up = ((tid & k) == 0);
        bool sw = up ? (a < bb) : (a > bb);   // descending overall
        if (sw) { ck[tid] = bb; ck[l] = a; }
      }
      __syncthreads();
    }
  }
  base[gi] = ck[tid];
}

// ------- merge_rank: exact global rank via binary searches -> emit center_pred -------
__global__ __launch_bounds__(1024) void merge_rank_kernel(
    const u64* __restrict__ keybuf, const u32* __restrict__ misc,
    const float* __restrict__ convr, float* __restrict__ center)
{
  __shared__ u64 sk[KEYCAP];
  int b = blockIdx.x;
  int tid = threadIdx.x;
  const u64* kb = keybuf + (size_t)b * KEYCAP;
  for (int i = tid; i < KEYCAP; i += 1024) sk[i] = kb[i];

  float* cb = center + (size_t)b * KTOP * 5;
  for (int i = tid; i < KTOP * 5; i += 1024) cb[i] = 0.f;
  __syncthreads();

  #pragma unroll
  for (int e = 0; e < KEYCAP / 1024; ++e) {
    int i = e * 1024 + tid;
    u64 k = sk[i];
    if (k == 0ULL) continue;
    int myc = i >> 10;
    int rank = i & 1023;
    #pragma unroll
    for (int c = 0; c < 8; ++c) {
      if (c == myc) continue;
      const u64* arr = &sk[c << 10];
      int lo = 0, hi = 1024;
      while (lo < hi) {
        int mid = (lo + hi) >> 1;
        if (arr[mid] > k) lo = mid + 1; else hi = mid;
      }
      rank += lo;
    }
    if (rank < KTOP) {
      u32 p = (~(u32)k) & 0xFFFFFu;
      float v = convr[(size_t)b * HW + p];
      float* o = cb + (size_t)rank * 5;
      o[0] = 1.0f;
      o[1] = (float)(p & (W - 1));
      o[2] = (float)(p >> 10);
      o[3] = v;
      o[4] = v;
    }
  }
}

extern "C" void kernel_launch(void* const* d_in, const int* in_sizes, int n_in,
                              void* d_out, int out_size, void* d_ws, size_t ws_size,
                              hipStream_t stream) {
  const float* in  = (const float*)d_in[0];
  const float* wc  = (const float*)d_in[1];
  const float* wsw = (const float*)d_in[2];

  float* out0   = (float*)d_out;                     // (8,3,1024,1024)
  float* center = out0 + (size_t)BATCH * 3 * HW;     // (8,2048,5)
  float* convr  = center + (size_t)BATCH * KTOP * 5; // (8,1,1024,1024)

  char* w = (char*)d_ws;
  u32* misc      = (u32*)(w + OFF_MISC);
  u64* passlist  = (u64*)(w + OFF_PASS);
  u64* checklist = (u64*)(w + OFF_CHK);
  u64* keybuf    = (u64*)(w + OFF_KEY);

  hipMemsetAsync(w, 0, OFF_PASS, stream);  // misc only (4 KB)

  conv_screen_kernel<<<dim3(W / TOX, H / TOY, BATCH), 256, 0, stream>>>(
      in, wc, wsw, out0, convr, passlist, checklist, misc);
  cutscan_kernel<<<BATCH, 1024, 0, stream>>>(passlist, misc);
  exact_kernel<<<dim3(16, BATCH), 1024, 0, stream>>>(
      in, wc, wsw, passlist, checklist, misc, keybuf);
  chunk_sort_kernel<<<dim3(KEYCAP / 1024, BATCH), 1024, 0, stream>>>(keybuf, misc);
  merge_rank_kernel<<<BATCH, 1024, 0, stream>>>(keybuf, misc, convr, center);
}